// Round 5
// baseline (193.183 us; speedup 1.0000x reference)
//
#include <hip/hip_runtime.h>
#include <math.h>

// Shapes fixed by setup_inputs(): B=8, N=8192, M=512 clusters, S=64 samples.
#define BB 8
#define NN 8192
#define MM 512
#define SS 64

// d_out layout (flat, return order, all read back as f32):
// new_xyz[8*512*3] | idx(as float)[8*512*64] | attention[8*512] | orientation[8*512]
#define OUT_IDX   (BB*MM*3)              // 12288
#define OUT_ATT   (OUT_IDX + BB*MM*SS)   // 274432
#define OUT_ORI   (OUT_ATT + BB*MM)      // 278528

typedef short v8s __attribute__((ext_vector_type(8)));   // 8 bf16 = 4 VGPRs (MFMA A/B frag)
typedef float v4f __attribute__((ext_vector_type(4)));   // MFMA C/D frag

static __device__ __forceinline__ unsigned short f2bf(float x) {
    unsigned int u = __float_as_uint(x);
    u += 0x7FFFu + ((u >> 16) & 1u);     // round-to-nearest-even
    return (unsigned short)(u >> 16);
}

// Single fused kernel: one block (256 thr) per cluster.
// Weights W2/W3 are consumed as bf16 via upper-ushort loads of the fp32 data
// (bf16-truncation): no packing pre-pass, no d_ws, single dispatch.
__global__ __launch_bounds__(256, 4) void feat3d_fused(
    const float* __restrict__ xyz,
    const float* __restrict__ W1, const float* __restrict__ b1,
    const float* __restrict__ W2, const float* __restrict__ b2,
    const float* __restrict__ W3, const float* __restrict__ b3,
    const float* __restrict__ W4, const float* __restrict__ b4,
    const float* __restrict__ W5, const float* __restrict__ b5,
    const float* __restrict__ Wa, const float* __restrict__ ba,
    const float* __restrict__ Wo, const float* __restrict__ bo,
    float* __restrict__ out)
{
    // LDS 27136 B (6-block capacity; occupancy is register-capped at 4).
    __shared__ __align__(16) unsigned char lds[27136];
    unsigned short* a2p = (unsigned short*)lds;            // h1 A-frags, 8 KB
    unsigned short* a3p = (unsigned short*)(lds + 8192);   // h2 A-frags, 16 KB
    float* smallf       = (float*)(lds + 24576);           // 512 floats, phased
    int* ls_idx         = (int*)(lds + 26624);             // 64 ints
    unsigned long long* ls_mask = (unsigned long long*)(lds + 26880); // [2][4]

    float* ls_g   = smallf;         // [64][4]  (BQ + L1)
    float* ls_w1  = smallf + 256;   // [64][4]  (L1)
    float* ls_v   = smallf;         // [256]    (pool -> L4; g dead)
    float* ls_par = smallf + 256;   // [256]    (L4 partials; w1 dead)
    float* ls_h5  = (float*)lds;    // [64]     (over a2p; dead after L2)

    const int t   = threadIdx.x;
    const int wv  = t >> 6;        // wave 0..3
    const int l   = t & 63;        // lane
    const int q   = l >> 4;        // quad 0..3
    const int r16 = l & 15;
    const int blk = blockIdx.x;
    const int b   = blk >> 9;
    const int m   = blk & 511;
    const float* xb = xyz + (size_t)b * (NN * 3);

    const float cx = xb[m*3+0], cy = xb[m*3+1], cz = xb[m*3+2];

    if (t < 3) out[(b*MM + m)*3 + t] = xb[m*3 + t];   // new_xyz

    // Stage W1^T + b1 early (independent of ball query; overlaps its latency).
    if (t < 64) {
        ls_w1[t*4+0] = W1[t];
        ls_w1[t*4+1] = W1[64 + t];
        ls_w1[t*4+2] = W1[128 + t];
        ls_w1[t*4+3] = b1[t];
    }

    // ---- Ball query with FUSED gather (all 4 waves, 256 pts/iter):
    // first 64 indices with d2 < 4.0 (by index); the valid lane already holds
    // dx,dy,dz so g=(p-c)/2 is written during the scan. Pads come from slot 0
    // (= globally first valid; nonempty since the center is its own neighbor).
    int cnt = 0;
    {
        int base = 0, pb = 0;
        while (base < NN && cnt < SS) {
            const int j = base + t;
            const float dx = xb[j*3+0] - cx;
            const float dy = xb[j*3+1] - cy;
            const float dz = xb[j*3+2] - cz;
            // no fma contraction: idx must be exact at the d2==4.0 boundary
            const float d2 = __fadd_rn(__fadd_rn(__fmul_rn(dx,dx), __fmul_rn(dy,dy)),
                                       __fmul_rn(dz,dz));
            const bool valid = d2 < 4.0f;
            const unsigned long long mask = __ballot(valid);
            if (l == 0) ls_mask[pb*4 + wv] = mask;
            __syncthreads();
            const unsigned long long m0 = ls_mask[pb*4+0], m1 = ls_mask[pb*4+1],
                                     m2 = ls_mask[pb*4+2], m3 = ls_mask[pb*4+3];
            int below = __popcll(mask & ((1ull << l) - 1ull));
            if (wv > 0) below += (int)__popcll(m0);
            if (wv > 1) below += (int)__popcll(m1);
            if (wv > 2) below += (int)__popcll(m2);
            const int pos = cnt + below;
            if (valid && pos < SS) {
                ls_idx[pos]   = j;
                ls_g[pos*4+0] = dx * 0.5f;
                ls_g[pos*4+1] = dy * 0.5f;
                ls_g[pos*4+2] = dz * 0.5f;
            }
            cnt += (int)(__popcll(m0) + __popcll(m1) + __popcll(m2) + __popcll(m3));
            if (cnt > SS) cnt = SS;
            base += 256;
            pb ^= 1;               // double-buffered masks: no trailing barrier
        }
    }
    __syncthreads();
    if (t < SS && t >= cnt) {      // pad with first neighbor (slot 0)
        ls_idx[t]   = ls_idx[0];
        ls_g[t*4+0] = ls_g[0];
        ls_g[t*4+1] = ls_g[1];
        ls_g[t*4+2] = ls_g[2];
    }
    __syncthreads();
    if (t < 64) out[OUT_IDX + (b*MM + m)*SS + t] = (float)ls_idx[t];

    // ---- L1 (fp32) + pack h1 into A-fragment layout:
    // lane l of wave wv produces s = wv*16+r16, c = kt*32+q*8+j  (2 frags) ----
    {
        const int s = wv*16 + r16;
        const float4 g4 = *(const float4*)&ls_g[s*4];
        #pragma unroll
        for (int kt = 0; kt < 2; ++kt) {
            union { unsigned short u[8]; v8s v; } fr;
            #pragma unroll
            for (int j = 0; j < 8; ++j) {
                const int c = kt*32 + q*8 + j;
                const float4 w = *(const float4*)&ls_w1[c*4];
                const float h = fmaf(g4.x, w.x, fmaf(g4.y, w.y, fmaf(g4.z, w.z, w.w)));
                fr.u[j] = f2bf(fmaxf(h, 0.f));
            }
            *(v8s*)&a2p[((kt*4 + wv)*64 + l)*8] = fr.v;
        }
    }
    __syncthreads();

    // ---- L2 MFMA: h2(64x128) = relu(h1 @ W2 + b2). Wave wv owns nt {2wv,2wv+1}.
    // B-frags read directly from fp32 W2 as upper-ushort (bf16 truncate).
    {
        const unsigned short* W2h = (const unsigned short*)W2;  // elem e -> 2e+1
        v8s bfr[2][2];
        #pragma unroll
        for (int kt = 0; kt < 2; ++kt)
            #pragma unroll
            for (int ni = 0; ni < 2; ++ni) {
                const int c2 = (2*wv + ni)*16 + r16;
                union { unsigned short u[8]; v8s v; } f;
                #pragma unroll
                for (int j = 0; j < 8; ++j)
                    f.u[j] = W2h[2*((kt*32 + q*8 + j)*128 + c2) + 1];
                bfr[kt][ni] = f.v;
            }

        const v4f z = {0.f, 0.f, 0.f, 0.f};
        v4f acc[4][2];
        #pragma unroll
        for (int mt = 0; mt < 4; ++mt) { acc[mt][0] = z; acc[mt][1] = z; }

        #pragma unroll
        for (int kt = 0; kt < 2; ++kt)
            #pragma unroll
            for (int mt = 0; mt < 4; ++mt) {
                const v8s a = *(const v8s*)&a2p[((kt*4 + mt)*64 + l)*8];
                #pragma unroll
                for (int ni = 0; ni < 2; ++ni)
                    acc[mt][ni] = __builtin_amdgcn_mfma_f32_16x16x32_bf16(
                        a, bfr[kt][ni], acc[mt][ni], 0, 0, 0);
            }

        // Epilogue: +b2, relu, cvt bf16, scatter into L3 A-frag layout.
        // C/D elem (mt,ni,rg): s = mt*16+q*4+rg, c2 = (2wv+ni)*16+r16.
        #pragma unroll
        for (int ni = 0; ni < 2; ++ni) {
            const int c2  = (2*wv + ni)*16 + r16;
            const float bias = b2[c2];
            const int kt3 = c2 >> 5;
            const int lhi = ((c2 >> 3) & 3) << 4;
            const int j3  = c2 & 7;
            #pragma unroll
            for (int mt = 0; mt < 4; ++mt)
                #pragma unroll
                for (int rg = 0; rg < 4; ++rg) {
                    const float h = fmaxf(acc[mt][ni][rg] + bias, 0.f);
                    const int s15 = q*4 + rg;
                    a3p[((kt3*4 + mt)*64 + (lhi | s15))*8 + j3] = f2bf(h);
                }
        }
    }
    __syncthreads();

    // ---- L3 MFMA: h3raw(64x256) = h2 @ W3. Wave wv owns nt {4wv..4wv+3}.
    //      B-frags streamed per-kt from fp32 W3 (upper-ushort). Pool in regs. ----
    {
        const unsigned short* W3h = (const unsigned short*)W3;
        const v4f z = {0.f, 0.f, 0.f, 0.f};
        v4f acc[4][4];
        #pragma unroll
        for (int mt = 0; mt < 4; ++mt)
            #pragma unroll
            for (int ni = 0; ni < 4; ++ni) acc[mt][ni] = z;

        #pragma unroll
        for (int kt = 0; kt < 4; ++kt) {
            v8s a[4], bb[4];
            #pragma unroll
            for (int mt = 0; mt < 4; ++mt)
                a[mt] = *(const v8s*)&a3p[((kt*4 + mt)*64 + l)*8];
            #pragma unroll
            for (int ni = 0; ni < 4; ++ni) {
                const int c3 = (4*wv + ni)*16 + r16;
                union { unsigned short u[8]; v8s v; } f;
                #pragma unroll
                for (int j = 0; j < 8; ++j)
                    f.u[j] = W3h[2*((kt*32 + q*8 + j)*256 + c3) + 1];
                bb[ni] = f.v;
            }
            #pragma unroll
            for (int mt = 0; mt < 4; ++mt)
                #pragma unroll
                for (int ni = 0; ni < 4; ++ni)
                    acc[mt][ni] = __builtin_amdgcn_mfma_f32_16x16x32_bf16(
                        a[mt], bb[ni], acc[mt][ni], 0, 0, 0);
        }

        // Pool over s: lane holds rows s = mt*16+q*4+rg for col c = (4wv+ni)*16+r16.
        // bias+relu after pool (relu monotone, bias per-column => commutes).
        #pragma unroll
        for (int ni = 0; ni < 4; ++ni) {
            float mx = acc[0][ni][0];
            #pragma unroll
            for (int mt = 0; mt < 4; ++mt)
                #pragma unroll
                for (int rg = 0; rg < 4; ++rg)
                    mx = fmaxf(mx, acc[mt][ni][rg]);
            mx = fmaxf(mx, __shfl_xor(mx, 16));
            mx = fmaxf(mx, __shfl_xor(mx, 32));
            if (q == 0) {
                const int c = (4*wv + ni)*16 + r16;
                ls_v[c] = fmaxf(mx + b3[c], 0.f);
            }
        }
    }
    __syncthreads();

    // ---- L4: 256 -> 128 (fp32, no relu), split-k over 2 thread halves ----
    {
        const int c  = t & 127;
        const int hf = t >> 7;
        float acc = hf ? 0.f : b4[c];
        const float* vsrc = ls_v + hf*128;
        const float* wsrc = W4 + (size_t)(hf*128)*128 + c;
        #pragma unroll 8
        for (int k = 0; k < 128; ++k)
            acc = fmaf(vsrc[k], wsrc[k*128], acc);
        ls_par[t] = acc;
    }
    __syncthreads();

    // ---- L5: 128 -> 64 (fp32, no relu), combining L4 halves inline ----
    if (t < 64) {
        float acc = b5[t];
        #pragma unroll 8
        for (int k = 0; k < 128; ++k)
            acc = fmaf(ls_par[k] + ls_par[128 + k], W5[k*64 + t], acc);
        ls_h5[t] = acc;
    }
    __syncthreads();

    // ---- Heads: attention = softplus(h5·Wa+ba); orientation = atan2(o1,o0)
    //      (normalization of o is scale-invariant under atan2 -> skipped) ----
    if (t < 64) {
        const float hv = ls_h5[t];
        float va = hv * Wa[t];
        float v0 = hv * Wo[2*t + 0];
        float v1 = hv * Wo[2*t + 1];
        #pragma unroll
        for (int off = 32; off > 0; off >>= 1) {
            va += __shfl_down(va, off);
            v0 += __shfl_down(v0, off);
            v1 += __shfl_down(v1, off);
        }
        if (t == 0) {
            const float a = va + ba[0];
            const float att = fmaxf(a, 0.f) + log1pf(expf(-fabsf(a)));
            out[OUT_ATT + b*MM + m] = att;
            out[OUT_ORI + b*MM + m] = atan2f(v1 + bo[1], v0 + bo[0]);
        }
    }
}

extern "C" void kernel_launch(void* const* d_in, const int* in_sizes, int n_in,
                              void* d_out, int out_size, void* d_ws, size_t ws_size,
                              hipStream_t stream) {
    const float* xyz = (const float*)d_in[0];
    const float* W1  = (const float*)d_in[1];
    const float* b1  = (const float*)d_in[2];
    const float* W2  = (const float*)d_in[3];
    const float* b2  = (const float*)d_in[4];
    const float* W3  = (const float*)d_in[5];
    const float* b3  = (const float*)d_in[6];
    const float* W4  = (const float*)d_in[7];
    const float* b4  = (const float*)d_in[8];
    const float* W5  = (const float*)d_in[9];
    const float* b5  = (const float*)d_in[10];
    const float* Wa  = (const float*)d_in[11];
    const float* ba  = (const float*)d_in[12];
    const float* Wo  = (const float*)d_in[13];
    const float* bo  = (const float*)d_in[14];

    feat3d_fused<<<dim3(BB*MM), dim3(256), 0, stream>>>(
        xyz, W1, b1, W2, b2, W3, b3, W4, b4, W5, b5, Wa, ba, Wo, bo,
        (float*)d_out);
}

// Round 6
// 138.953 us; speedup vs baseline: 1.3903x; 1.3903x over previous
//
#include <hip/hip_runtime.h>
#include <math.h>

// Shapes fixed by setup_inputs(): B=8, N=8192, M=512 clusters, S=64 samples.
#define BB 8
#define NN 8192
#define MM 512
#define SS 64
#define NCLUST (BB*MM)                 // 4096

// d_out layout (flat, return order, all read back as f32):
// new_xyz[8*512*3] | idx(as float)[8*512*64] | attention[8*512] | orientation[8*512]
#define OUT_IDX   (BB*MM*3)            // 12288
#define OUT_ATT   (OUT_IDX + BB*MM*SS) // 274432
#define OUT_ORI   (OUT_ATT + BB*MM)    // 278528

// d_ws layout (ushorts): [0,8192) W2 B-frags | [8192,40960) W3 B-frags |
// [40960, 40960+4096*256) pooled v (bf16). Total ~2.08 MB.
#define WS_W3 8192
#define WS_V  40960

typedef short v8s __attribute__((ext_vector_type(8)));   // 8 bf16 (MFMA A/B frag)
typedef float v4f __attribute__((ext_vector_type(4)));   // MFMA C/D frag

static __device__ __forceinline__ unsigned short f2bf(float x) {
    unsigned int u = __float_as_uint(x);
    u += 0x7FFFu + ((u >> 16) & 1u);     // round-to-nearest-even
    return (unsigned short)(u >> 16);
}

// ---- Kernel 0: pack W2 (64x128) and W3 (128x256) fp32 -> bf16 MFMA B-frag
// layout. B-frag lane l holds B[kt*32+(l>>4)*8+j][nt*16+(l&15)], j=0..7,
// stored contiguous (16 B/lane) so the main kernel loads one dwordx4/frag.
__global__ void pack_weights(const float* __restrict__ W2,
                             const float* __restrict__ W3,
                             unsigned short* __restrict__ ws)
{
    const int gid = blockIdx.x * 256 + threadIdx.x;    // 0..5119
    const float* W; unsigned short* dst; int N, kt, nt, lane;
    if (gid < 1024) {                   // W2: 16 tiles * 64 lanes
        W = W2; N = 128;
        const int tile = gid >> 6; lane = gid & 63;
        kt = tile >> 3; nt = tile & 7;
        dst = ws + (size_t)(tile * 64 + lane) * 8;
    } else {                            // W3: 64 tiles * 64 lanes
        const int g = gid - 1024;
        W = W3; N = 256;
        const int tile = g >> 6; lane = g & 63;
        kt = tile >> 4; nt = tile & 15;
        dst = ws + WS_W3 + (size_t)(tile * 64 + lane) * 8;
    }
    const int k0 = kt * 32 + (lane >> 4) * 8;
    const int n  = nt * 16 + (lane & 15);
    union { unsigned short u[8]; v8s v; } f;
    #pragma unroll
    for (int j = 0; j < 8; ++j) f.u[j] = f2bf(W[(k0 + j) * N + n]);
    *(v8s*)dst = f.v;
}

// ---- Phase A: per-cluster BQ + gather + L1 + L2/L3 MFMA + pool -> v (bf16) ----
__global__ __launch_bounds__(256, 4) void feat3d_front(
    const float* __restrict__ xyz,
    const float* __restrict__ W1, const float* __restrict__ b1,
    const float* __restrict__ b2, const float* __restrict__ b3,
    const unsigned short* __restrict__ Wp,
    unsigned short* __restrict__ vdst,
    float* __restrict__ out)
{
    __shared__ __align__(16) unsigned char lds[27200];
    unsigned short* a2p = (unsigned short*)lds;            // h1 A-frags, 8 KB
    unsigned short* a3p = (unsigned short*)(lds + 8192);   // h2 A-frags, 16 KB
    float* smallf       = (float*)(lds + 24576);           // 512 f32: g | w1
    int* ls_idx         = (int*)(lds + 26624);             // 64
    unsigned long long* ls_mask = (unsigned long long*)(lds + 26880); // [2][4]

    float* ls_g  = smallf;         // [64][4]
    float* ls_w1 = smallf + 256;   // [64][4]

    const int t   = threadIdx.x;
    const int wv  = t >> 6;
    const int l   = t & 63;
    const int q   = l >> 4;
    const int r16 = l & 15;
    const int blk = blockIdx.x;
    const int b   = blk >> 9;
    const int m   = blk & 511;
    const float* xb = xyz + (size_t)b * (NN * 3);

    // Prefetch W2 B-frags NOW (packed, one dwordx4 each); they stay in flight
    // through the ball query (reg loads aren't drained by __syncthreads).
    const v8s* W2f = (const v8s*)Wp;
    v8s bfr[2][2];
    #pragma unroll
    for (int kt = 0; kt < 2; ++kt)
        #pragma unroll
        for (int ni = 0; ni < 2; ++ni)
            bfr[kt][ni] = W2f[(kt*8 + 2*wv + ni)*64 + l];

    const float cx = xb[m*3+0], cy = xb[m*3+1], cz = xb[m*3+2];

    if (t < 3) out[(b*MM + m)*3 + t] = xb[m*3 + t];   // new_xyz

    // Stage W1^T + b1 early (overlaps BQ latency).
    if (t < 64) {
        ls_w1[t*4+0] = W1[t];
        ls_w1[t*4+1] = W1[64 + t];
        ls_w1[t*4+2] = W1[128 + t];
        ls_w1[t*4+3] = b1[t];
    }

    // ---- Ball query with fused gather (256 pts/iter): first 64 idx with
    // d2 < 4.0 (by index); valid lane already holds dx,dy,dz so g is written
    // during the scan. Pads copy slot 0 (= globally first valid). ----
    int cnt = 0;
    {
        int base = 0, pb = 0;
        while (base < NN && cnt < SS) {
            const int j = base + t;
            const float dx = xb[j*3+0] - cx;
            const float dy = xb[j*3+1] - cy;
            const float dz = xb[j*3+2] - cz;
            // no fma contraction: idx must be exact at the d2==4.0 boundary
            const float d2 = __fadd_rn(__fadd_rn(__fmul_rn(dx,dx), __fmul_rn(dy,dy)),
                                       __fmul_rn(dz,dz));
            const bool valid = d2 < 4.0f;
            const unsigned long long mask = __ballot(valid);
            if (l == 0) ls_mask[pb*4 + wv] = mask;
            __syncthreads();
            const unsigned long long m0 = ls_mask[pb*4+0], m1 = ls_mask[pb*4+1],
                                     m2 = ls_mask[pb*4+2], m3 = ls_mask[pb*4+3];
            int below = __popcll(mask & ((1ull << l) - 1ull));
            if (wv > 0) below += (int)__popcll(m0);
            if (wv > 1) below += (int)__popcll(m1);
            if (wv > 2) below += (int)__popcll(m2);
            const int pos = cnt + below;
            if (valid && pos < SS) {
                ls_idx[pos]   = j;
                ls_g[pos*4+0] = dx * 0.5f;
                ls_g[pos*4+1] = dy * 0.5f;
                ls_g[pos*4+2] = dz * 0.5f;
            }
            cnt += (int)(__popcll(m0) + __popcll(m1) + __popcll(m2) + __popcll(m3));
            if (cnt > SS) cnt = SS;
            base += 256;
            pb ^= 1;               // double-buffered masks
        }
    }
    __syncthreads();
    if (t < SS && t >= cnt) {      // pad with first neighbor (slot 0)
        ls_idx[t]   = ls_idx[0];
        ls_g[t*4+0] = ls_g[0];
        ls_g[t*4+1] = ls_g[1];
        ls_g[t*4+2] = ls_g[2];
    }
    __syncthreads();
    if (t < 64) out[OUT_IDX + (b*MM + m)*SS + t] = (float)ls_idx[t];

    // ---- L1 (fp32) + pack h1 into A-frag layout:
    // lane l of wave wv produces s = wv*16+r16, c = kt*32+q*8+j ----
    {
        const int s = wv*16 + r16;
        const float4 g4 = *(const float4*)&ls_g[s*4];
        #pragma unroll
        for (int kt = 0; kt < 2; ++kt) {
            union { unsigned short u[8]; v8s v; } fr;
            #pragma unroll
            for (int j = 0; j < 8; ++j) {
                const int c = kt*32 + q*8 + j;
                const float4 w = *(const float4*)&ls_w1[c*4];
                const float h = fmaf(g4.x, w.x, fmaf(g4.y, w.y, fmaf(g4.z, w.z, w.w)));
                fr.u[j] = f2bf(fmaxf(h, 0.f));
            }
            *(v8s*)&a2p[((kt*4 + wv)*64 + l)*8] = fr.v;
        }
    }
    __syncthreads();

    // ---- L2 MFMA: h2 = relu(h1 @ W2 + b2). Wave wv owns nt {2wv, 2wv+1}. ----
    {
        const v4f z = {0.f, 0.f, 0.f, 0.f};
        v4f acc[4][2];
        #pragma unroll
        for (int mt = 0; mt < 4; ++mt) { acc[mt][0] = z; acc[mt][1] = z; }

        #pragma unroll
        for (int kt = 0; kt < 2; ++kt)
            #pragma unroll
            for (int mt = 0; mt < 4; ++mt) {
                const v8s a = *(const v8s*)&a2p[((kt*4 + mt)*64 + l)*8];
                #pragma unroll
                for (int ni = 0; ni < 2; ++ni)
                    acc[mt][ni] = __builtin_amdgcn_mfma_f32_16x16x32_bf16(
                        a, bfr[kt][ni], acc[mt][ni], 0, 0, 0);
            }

        // Epilogue: +b2, relu, bf16, scatter into L3 A-frag layout.
        // C/D elem (mt,ni,rg): s = mt*16+q*4+rg, c2 = (2wv+ni)*16+r16.
        #pragma unroll
        for (int ni = 0; ni < 2; ++ni) {
            const int c2  = (2*wv + ni)*16 + r16;
            const float bias = b2[c2];
            const int kt3 = c2 >> 5;
            const int lhi = ((c2 >> 3) & 3) << 4;
            const int j3  = c2 & 7;
            #pragma unroll
            for (int mt = 0; mt < 4; ++mt)
                #pragma unroll
                for (int rg = 0; rg < 4; ++rg) {
                    const float h = fmaxf(acc[mt][ni][rg] + bias, 0.f);
                    const int s15 = q*4 + rg;
                    a3p[((kt3*4 + mt)*64 + (lhi | s15))*8 + j3] = f2bf(h);
                }
        }
    }
    __syncthreads();

    // ---- L3 MFMA in 2 passes (acc[4][2] keeps regs <=128 for 4 blk/CU).
    // Wave wv owns nt {4wv..4wv+3}; pass np covers nt0=4wv+2np, nt0+1.
    // B-frags software-pipelined one kt ahead. Pool in regs, v -> global bf16.
    {
        const v8s* W3f = (const v8s*)(Wp + WS_W3);
        const int cg = blk;                      // global cluster id = b*512+m
        unsigned short* vrow = vdst + (size_t)cg * 256;

        #pragma unroll
        for (int np = 0; np < 2; ++np) {
            const int nt0 = 4*wv + 2*np;
            const v4f z = {0.f, 0.f, 0.f, 0.f};
            v4f acc[4][2];
            #pragma unroll
            for (int mt = 0; mt < 4; ++mt) { acc[mt][0] = z; acc[mt][1] = z; }

            v8s bb0 = W3f[(0*16 + nt0    )*64 + l];
            v8s bb1 = W3f[(0*16 + nt0 + 1)*64 + l];
            #pragma unroll
            for (int kt = 0; kt < 4; ++kt) {
                v8s a[4];
                #pragma unroll
                for (int mt = 0; mt < 4; ++mt)
                    a[mt] = *(const v8s*)&a3p[((kt*4 + mt)*64 + l)*8];
                v8s nb0, nb1;
                if (kt < 3) {
                    nb0 = W3f[((kt+1)*16 + nt0    )*64 + l];
                    nb1 = W3f[((kt+1)*16 + nt0 + 1)*64 + l];
                }
                #pragma unroll
                for (int mt = 0; mt < 4; ++mt) {
                    acc[mt][0] = __builtin_amdgcn_mfma_f32_16x16x32_bf16(
                        a[mt], bb0, acc[mt][0], 0, 0, 0);
                    acc[mt][1] = __builtin_amdgcn_mfma_f32_16x16x32_bf16(
                        a[mt], bb1, acc[mt][1], 0, 0, 0);
                }
                if (kt < 3) { bb0 = nb0; bb1 = nb1; }
            }

            // Pool over s (16 regs + cross-quad shfl); bias+relu after pool
            // (relu monotone, bias per-column => commutes). Store bf16 v.
            #pragma unroll
            for (int ni = 0; ni < 2; ++ni) {
                float mx = acc[0][ni][0];
                #pragma unroll
                for (int mt = 0; mt < 4; ++mt)
                    #pragma unroll
                    for (int rg = 0; rg < 4; ++rg)
                        mx = fmaxf(mx, acc[mt][ni][rg]);
                mx = fmaxf(mx, __shfl_xor(mx, 16));
                mx = fmaxf(mx, __shfl_xor(mx, 32));
                if (q == 0) {
                    const int c = (nt0 + ni)*16 + r16;
                    vrow[c] = f2bf(fmaxf(mx + b3[c], 0.f));
                }
            }
        }
    }
}

// ---- Phase B: 16 clusters/block -> W4/W5 read 256x fewer times total.
// L4/L5 fp32 (accuracy headroom preserved); heads fused. ----
__global__ __launch_bounds__(256) void feat3d_tail(
    const unsigned short* __restrict__ vsrc,
    const float* __restrict__ W4, const float* __restrict__ b4,
    const float* __restrict__ W5, const float* __restrict__ b5,
    const float* __restrict__ Wa, const float* __restrict__ ba,
    const float* __restrict__ Wo, const float* __restrict__ bo,
    float* __restrict__ out)
{
    __shared__ __align__(16) float V[16][256];    // 16 KB
    __shared__ __align__(16) float H4[16][128];   // 8 KB
    __shared__ __align__(16) float H5[16][64];    // 4 KB

    const int t   = threadIdx.x;
    const int cl0 = blockIdx.x * 16;

    // Load V tile (bf16 -> f32), coalesced uint4 (8 shorts each, x2/thread).
    {
        const int i  = t >> 4;
        const int ch = t & 15;
        const uint4* src = (const uint4*)(vsrc + (size_t)(cl0 + i) * 256);
        #pragma unroll
        for (int h = 0; h < 2; ++h) {
            const uint4 r = src[ch*2 + h];
            const unsigned int u[4] = {r.x, r.y, r.z, r.w};
            #pragma unroll
            for (int j = 0; j < 4; ++j) {
                V[i][ch*16 + h*8 + 2*j]     = __uint_as_float(u[j] << 16);
                V[i][ch*16 + h*8 + 2*j + 1] = __uint_as_float(u[j] & 0xFFFF0000u);
            }
        }
    }
    __syncthreads();

    // L4: h4[i][c] = b4[c] + sum_k V[i][k] W4[k][c]; thread = (c, 8 clusters).
    {
        const int c  = t & 127;
        const int ih = t >> 7;
        float acc[8];
        #pragma unroll
        for (int i = 0; i < 8; ++i) acc[i] = b4[c];
        for (int k4 = 0; k4 < 64; ++k4) {
            const float w0 = W4[(4*k4+0)*128 + c];
            const float w1 = W4[(4*k4+1)*128 + c];
            const float w2 = W4[(4*k4+2)*128 + c];
            const float w3 = W4[(4*k4+3)*128 + c];
            #pragma unroll
            for (int i = 0; i < 8; ++i) {
                const float4 vv = *(const float4*)&V[ih*8 + i][4*k4];
                acc[i] = fmaf(vv.x, w0, fmaf(vv.y, w1,
                         fmaf(vv.z, w2, fmaf(vv.w, w3, acc[i]))));
            }
        }
        #pragma unroll
        for (int i = 0; i < 8; ++i) H4[ih*8 + i][c] = acc[i];
    }
    __syncthreads();

    // L5: h5[i][c] = b5[c] + sum_k H4[i][k] W5[k][c]; thread = (c, 4 clusters).
    {
        const int c  = t & 63;
        const int iq = t >> 6;
        float acc[4];
        #pragma unroll
        for (int i = 0; i < 4; ++i) acc[i] = b5[c];
        for (int k4 = 0; k4 < 32; ++k4) {
            const float w0 = W5[(4*k4+0)*64 + c];
            const float w1 = W5[(4*k4+1)*64 + c];
            const float w2 = W5[(4*k4+2)*64 + c];
            const float w3 = W5[(4*k4+3)*64 + c];
            #pragma unroll
            for (int i = 0; i < 4; ++i) {
                const float4 vv = *(const float4*)&H4[iq*4 + i][4*k4];
                acc[i] = fmaf(vv.x, w0, fmaf(vv.y, w1,
                         fmaf(vv.z, w2, fmaf(vv.w, w3, acc[i]))));
            }
        }
        #pragma unroll
        for (int i = 0; i < 4; ++i) H5[iq*4 + i][c] = acc[i];
    }
    __syncthreads();

    // Heads: wave wv handles clusters 4wv..4wv+3. attention = softplus(h5.Wa+ba);
    // orientation = atan2(o1,o0) (normalization is scale-invariant -> skipped).
    {
        const int wv = t >> 6, l = t & 63;
        const float wa  = Wa[l];
        const float wo0 = Wo[2*l + 0];
        const float wo1 = Wo[2*l + 1];
        #pragma unroll
        for (int i = 0; i < 4; ++i) {
            const float hv = H5[4*wv + i][l];
            float va = hv * wa;
            float v0 = hv * wo0;
            float v1 = hv * wo1;
            #pragma unroll
            for (int off = 32; off > 0; off >>= 1) {
                va += __shfl_down(va, off);
                v0 += __shfl_down(v0, off);
                v1 += __shfl_down(v1, off);
            }
            if (l == 0) {
                const int cg = cl0 + 4*wv + i;
                const float a = va + ba[0];
                out[OUT_ATT + cg] = fmaxf(a, 0.f) + log1pf(expf(-fabsf(a)));
                out[OUT_ORI + cg] = atan2f(v1 + bo[1], v0 + bo[0]);
            }
        }
    }
}

extern "C" void kernel_launch(void* const* d_in, const int* in_sizes, int n_in,
                              void* d_out, int out_size, void* d_ws, size_t ws_size,
                              hipStream_t stream) {
    const float* xyz = (const float*)d_in[0];
    const float* W1  = (const float*)d_in[1];
    const float* b1  = (const float*)d_in[2];
    const float* W2  = (const float*)d_in[3];
    const float* b2  = (const float*)d_in[4];
    const float* W3  = (const float*)d_in[5];
    const float* b3  = (const float*)d_in[6];
    const float* W4  = (const float*)d_in[7];
    const float* b4  = (const float*)d_in[8];
    const float* W5  = (const float*)d_in[9];
    const float* b5  = (const float*)d_in[10];
    const float* Wa  = (const float*)d_in[11];
    const float* ba  = (const float*)d_in[12];
    const float* Wo  = (const float*)d_in[13];
    const float* bo  = (const float*)d_in[14];

    unsigned short* ws = (unsigned short*)d_ws;

    pack_weights<<<dim3(20), dim3(256), 0, stream>>>(W2, W3, ws);
    feat3d_front<<<dim3(NCLUST), dim3(256), 0, stream>>>(
        xyz, W1, b1, b2, b3, ws, ws + WS_V, (float*)d_out);
    feat3d_tail<<<dim3(NCLUST/16), dim3(256), 0, stream>>>(
        ws + WS_V, W4, b4, W5, b5, Wa, ba, Wo, bo, (float*)d_out);
}